// Round 5
// baseline (327.455 us; speedup 1.0000x reference)
//
#include <hip/hip_runtime.h>

// Problem constants (GlobalPointer: B=16, L=512, H=1024, HEADS=12, D=64)
#define BB 16
#define LL 512
#define HH 1024
#define HEADS 12
#define DD 64
#define N1 1536   // HEADS * 2 * DD
#define M1 8192   // BB * LL
#define NEGC 1e12f

typedef short bf16x8 __attribute__((ext_vector_type(8)));
typedef float f32x4 __attribute__((ext_vector_type(4)));

typedef const __attribute__((address_space(1))) unsigned int glob_u32;
typedef __attribute__((address_space(3))) unsigned int lds_u32;

__device__ __forceinline__ void gl_lds16(const unsigned short* g, unsigned short* l) {
    __builtin_amdgcn_global_load_lds((glob_u32*)g, (lds_u32*)l, 16, 0, 0);
}

__device__ __forceinline__ unsigned short f2bf(float f) {
    union { float f; unsigned int u; } v; v.f = f;
    unsigned int u = v.u;
    return (unsigned short)((u + 0x7fffu + ((u >> 16) & 1u)) >> 16);
}

// ---------------- Kernel 1: X fp32 -> bf16 (8192x1024) ----------------
__global__ __launch_bounds__(256) void k_conv_x(const float* __restrict__ X,
                                                unsigned short* __restrict__ Xb,
                                                int n4) {
    int i = blockIdx.x * 256 + threadIdx.x;
    if (i >= n4) return;
    float4 v = ((const float4*)X)[i];
    ushort4 o;
    o.x = f2bf(v.x); o.y = f2bf(v.y); o.z = f2bf(v.z); o.w = f2bf(v.w);
    ((ushort4*)Xb)[i] = o;
}

// ------------- Kernel 2: W (1024x1536 f32) -> Wt (1536x1024 bf16) -------------
__global__ __launch_bounds__(256) void k_trans_w(const float* __restrict__ W,
                                                 unsigned short* __restrict__ Wt) {
    __shared__ float tile[32][33];
    int n0 = blockIdx.x * 32;
    int k0 = blockIdx.y * 32;
    int tx = threadIdx.x;   // 0..31
    int ty = threadIdx.y;   // 0..7
#pragma unroll
    for (int i = 0; i < 4; i++) {
        int k = ty + i * 8;
        tile[k][tx] = W[(size_t)(k0 + k) * N1 + n0 + tx];
    }
    __syncthreads();
#pragma unroll
    for (int i = 0; i < 4; i++) {
        int n = ty + i * 8;
        Wt[(size_t)(n0 + n) * HH + k0 + tx] = f2bf(tile[tx][n]);
    }
}

// ------------- Kernel 3: C = Xb @ Wt^T (+bias, RoPE) -> Qr, Kr (bf16) -------------
// 128x128 tile, BK=32, async staging (m97 pattern, ran on HW in R2). Operands
// SWAPPED: acc = mfma(Wfrag, Xfrag) -> D: col(lane&15)=m, row(quad*4+reg)=n.
// Each lane holds 4 consecutive n (=d channel) -> RoPE pairs in-lane, 8B stores.
__global__ __launch_bounds__(256) void k_gemm1_rope(
    const unsigned short* __restrict__ Xb,   // [8192][1024]
    const unsigned short* __restrict__ Wt,   // [1536][1024]
    const float* __restrict__ bias,          // [1536]
    const float* __restrict__ pe,            // [512][64]  pe[l][2i]=sin, [2i+1]=cos
    unsigned short* __restrict__ Qr,         // [B*HEADS*512][64]
    unsigned short* __restrict__ Kr)
{
    __shared__ __align__(16) unsigned short As[128 * 32];   // X rows (m)
    __shared__ __align__(16) unsigned short Bs[128 * 32];   // W rows (n)
    int m0 = blockIdx.y * 128;
    int n0 = blockIdx.x * 128;
    int tid = threadIdx.x;
    int w  = tid >> 6;
    int ln = tid & 63;
    int lq = ln >> 4;       // quad
    int lm = ln & 15;
    int wm = (w & 1) * 64;
    int wn = (w >> 1) * 64;

    int lrow = ln >> 2;          // 0..15
    int lcol = (ln & 3) * 8;
    const unsigned short* ga0 = &Xb[(size_t)(m0 + w * 32 + lrow) * HH + lcol];
    const unsigned short* ga1 = ga0 + (size_t)16 * HH;
    const unsigned short* gb0 = &Wt[(size_t)(n0 + w * 32 + lrow) * HH + lcol];
    const unsigned short* gb1 = gb0 + (size_t)16 * HH;
    unsigned short* la0 = &As[(w * 32) * 32];
    unsigned short* la1 = la0 + 16 * 32;
    unsigned short* lb0 = &Bs[(w * 32) * 32];
    unsigned short* lb1 = lb0 + 16 * 32;

    const unsigned short* px = &As[(wm + lm) * 32];
    const unsigned short* pw = &Bs[(wn + lm) * 32];

    f32x4 acc[4][4] = {};   // [ti=m-tile][tj=n-tile]

    for (int kk = 0; kk < HH; kk += 32) {
        gl_lds16(ga0 + kk, la0);
        gl_lds16(ga1 + kk, la1);
        gl_lds16(gb0 + kk, lb0);
        gl_lds16(gb1 + kk, lb1);
        __syncthreads();

        bf16x8 xf[4], wf[4];
#pragma unroll
        for (int t = 0; t < 4; t++) {
            xf[t] = *(const bf16x8*)&px[t * 16 * 32 + lq * 8];
            wf[t] = *(const bf16x8*)&pw[t * 16 * 32 + lq * 8];
        }
#pragma unroll
        for (int ti = 0; ti < 4; ti++)
#pragma unroll
            for (int tj = 0; tj < 4; tj++)
                acc[ti][tj] = __builtin_amdgcn_mfma_f32_16x16x32_bf16(wf[tj], xf[ti], acc[ti][tj], 0, 0, 0);
        __syncthreads();
    }

    // Epilogue: lane holds n = nb..nb+3 (consecutive d) for m = ...+lm.
#pragma unroll
    for (int tj = 0; tj < 4; tj++) {
        int nb = n0 + wn + tj * 16 + lq * 4;    // multiple of 4
        float4 b4 = *(const float4*)&bias[nb];
        int h  = nb >> 7;
        int c  = nb & 127;
        int jb = c & 63;
        bool isK = (c >= 64);                    // wave-uniform per tj tile
        unsigned short* dst = isK ? Kr : Qr;
        size_t hoff = (size_t)h * LL * DD + jb;
#pragma unroll
        for (int ti = 0; ti < 4; ti++) {
            int m = m0 + wm + ti * 16 + lm;
            int l = m & (LL - 1);
            int bidx = m >> 9;
            float4 p4 = *(const float4*)&pe[l * 64 + jb];  // (s0,c0,s1,c1)
            float v0 = acc[ti][tj][0] + b4.x;
            float v1 = acc[ti][tj][1] + b4.y;
            float v2 = acc[ti][tj][2] + b4.z;
            float v3 = acc[ti][tj][3] + b4.w;
            ushort4 st;
            st.x = f2bf(v0 * p4.y - v1 * p4.x);
            st.y = f2bf(v1 * p4.y + v0 * p4.x);
            st.z = f2bf(v2 * p4.w - v3 * p4.z);
            st.w = f2bf(v3 * p4.w + v2 * p4.z);
            *(ushort4*)&dst[(size_t)bidx * HEADS * LL * DD + hoff + (size_t)l * DD] = st;
        }
    }
}

// ------------- Kernel 4: logits = Q @ K^T, mask, /8 -------------
// 128x128 tile per block, K=64 as two [128][32] panels. Staging via explicit
// uint4 loads + LDS vector writes (R1-proven style; hedge vs one-shot
// global_load_lds burst). Swapped operands -> float4 stores.
__global__ __launch_bounds__(256) void k_gemm2(
    const unsigned short* __restrict__ Qr,
    const unsigned short* __restrict__ Kr,
    const int* __restrict__ mask,            // [B][L]
    float* __restrict__ out)                 // [B][HEADS][L][L]
{
    __shared__ __align__(16) unsigned short Qs[2][128 * 32];
    __shared__ __align__(16) unsigned short Ks[2][128 * 32];
    int bh = blockIdx.z;
    int b  = bh / HEADS;
    int n0 = blockIdx.x * 128;
    int m0 = blockIdx.y * 128;
    int tid = threadIdx.x;
    int w  = tid >> 6;
    int ln = tid & 63;
    int lq = ln >> 4;
    int lm = ln & 15;
    int wm = (w & 1) * 64;
    int wn = (w >> 1) * 64;

    const unsigned short* Qb = Qr + (size_t)bh * LL * DD;
    const unsigned short* Kb = Kr + (size_t)bh * LL * DD;

    int row  = tid >> 3;          // 0..31
    int colq = tid & 7;           // 8-elem segment
    int pp   = colq >> 2;         // panel
    int cc   = (colq & 3) * 8;    // within-panel col
#pragma unroll
    for (int rr = 0; rr < 128; rr += 32) {
        uint4 qv = *(const uint4*)&Qb[(size_t)(m0 + rr + row) * DD + colq * 8];
        uint4 kv = *(const uint4*)&Kb[(size_t)(n0 + rr + row) * DD + colq * 8];
        *(uint4*)&Qs[pp][(rr + row) * 32 + cc] = qv;
        *(uint4*)&Ks[pp][(rr + row) * 32 + cc] = kv;
    }
    __syncthreads();

    f32x4 acc[4][4] = {};   // [tm][tn]
#pragma unroll
    for (int p = 0; p < 2; p++) {
        bf16x8 kf[4], qf[4];
#pragma unroll
        for (int t = 0; t < 4; t++) {
            kf[t] = *(const bf16x8*)&Ks[p][(wn + t * 16 + lm) * 32 + lq * 8];
            qf[t] = *(const bf16x8*)&Qs[p][(wm + t * 16 + lm) * 32 + lq * 8];
        }
#pragma unroll
        for (int tm = 0; tm < 4; tm++)
#pragma unroll
            for (int tn = 0; tn < 4; tn++)
                acc[tm][tn] = __builtin_amdgcn_mfma_f32_16x16x32_bf16(kf[tn], qf[tm], acc[tm][tn], 0, 0, 0);
    }

#pragma unroll
    for (int tn = 0; tn < 4; tn++) {
        int nb = n0 + wn + tn * 16 + lq * 4;
        int4 mv = *(const int4*)&mask[b * LL + nb];
        float pm0 = (float)mv.x, pm1 = (float)mv.y, pm2 = (float)mv.z, pm3 = (float)mv.w;
        float ng0 = (1.0f - pm0) * NEGC, ng1 = (1.0f - pm1) * NEGC;
        float ng2 = (1.0f - pm2) * NEGC, ng3 = (1.0f - pm3) * NEGC;
#pragma unroll
        for (int tm = 0; tm < 4; tm++) {
            int m = m0 + wm + tm * 16 + lm;
            float4 val;
            val.x = (acc[tm][tn][0] * pm0 - ng0 - (nb     < m ? NEGC : 0.0f)) * 0.125f;
            val.y = (acc[tm][tn][1] * pm1 - ng1 - (nb + 1 < m ? NEGC : 0.0f)) * 0.125f;
            val.z = (acc[tm][tn][2] * pm2 - ng2 - (nb + 2 < m ? NEGC : 0.0f)) * 0.125f;
            val.w = (acc[tm][tn][3] * pm3 - ng3 - (nb + 3 < m ? NEGC : 0.0f)) * 0.125f;
            *(float4*)&out[((size_t)bh * LL + m) * LL + nb] = val;
        }
    }
}

extern "C" void kernel_launch(void* const* d_in, const int* in_sizes, int n_in,
                              void* d_out, int out_size, void* d_ws, size_t ws_size,
                              hipStream_t stream) {
    const float* X    = (const float*)d_in[0];   // (16,512,1024)
    const int*   mask = (const int*)d_in[1];     // (16,512)
    const float* W    = (const float*)d_in[2];   // (1024,1536)
    const float* bias = (const float*)d_in[3];   // (1536,)
    const float* pe   = (const float*)d_in[4];   // (512,64)
    float* out = (float*)d_out;

    char* ws = (char*)d_ws;
    unsigned short* Xb = (unsigned short*)ws;                                // 16.78 MB
    unsigned short* Wt = (unsigned short*)(ws + 16777216);                   // 3.15 MB
    unsigned short* Qr = (unsigned short*)(ws + 16777216 + 3145728);         // 12.58 MB
    unsigned short* Kr = Qr + (size_t)BB * HEADS * LL * DD;                  // 12.58 MB

    k_conv_x<<<dim3((M1 * HH / 4 + 255) / 256), dim3(256), 0, stream>>>(X, Xb, M1 * HH / 4);
    k_trans_w<<<dim3(N1 / 32, HH / 32), dim3(32, 8), 0, stream>>>(W, Wt);
    k_gemm1_rope<<<dim3(N1 / 128, M1 / 128), dim3(256), 0, stream>>>(Xb, Wt, bias, pe, Qr, Kr);
    k_gemm2<<<dim3(LL / 128, LL / 128, BB * HEADS), dim3(256), 0, stream>>>(Qr, Kr, mask, out);
}